// Round 18
// baseline (133.420 us; speedup 1.0000x reference)
//
#include <hip/hip_runtime.h>

#define N_NODES 16384
#define N_EDGES 262144
#define D 256
#define B_GRAPHS 32
#define NODES_PER_GRAPH 512   // N_NODES / B_GRAPHS
#define MAXDEG 64             // Poisson(16): P(deg>64) ~ 1e-17
#define NWARM 36              // 36 blocks x 64KB = 2.25MB = all 9 weight mats

// ---------------------------------------------------------------------------
// zero cnt
// ---------------------------------------------------------------------------
__global__ __launch_bounds__(256) void zero_cnt_kernel(int* __restrict__ cnt) {
    cnt[blockIdx.x * 256 + threadIdx.x] = 0;
}

// ---------------------------------------------------------------------------
// bucket fill: col[dst*64 + slot] = src
// ---------------------------------------------------------------------------
__global__ __launch_bounds__(256) void fill_bucket_kernel(const int* __restrict__ edge,
                                                          int* __restrict__ cnt,
                                                          int* __restrict__ col) {
    int e = blockIdx.x * 256 + threadIdx.x;
    int dst = edge[N_EDGES + e];
    int src = edge[e];
    int slot = atomicAdd(&cnt[dst], 1);
    if (slot < MAXDEG) col[dst * MAXDEG + slot] = src;
}

// ---------------------------------------------------------------------------
// aggx: blocks [0,4096): A[i] = mean_{j in in(i)} x[j]  (one wave per node)
//       blocks [4096,4132): read-touch all weight matrices -> warm L3 so the
//       latency-bound tail hits L3 (~450cy) instead of HBM (~900cy). The
//       harness's 268MB poison fills evict L3 every replay (R17 counters:
//       tail FETCH 17MB warm), so this re-warms per replay inside an
//       existing dispatch (no new boundary).
// ---------------------------------------------------------------------------
__global__ __launch_bounds__(256) void aggx_kernel(const float* __restrict__ x,
                                                   const int* __restrict__ cnt,
                                                   const int* __restrict__ col,
                                                   float* __restrict__ A,
                                                   const float* __restrict__ Wl,
                                                   const float* __restrict__ Wr,
                                                   const float* __restrict__ Wh,
                                                   const float* __restrict__ Wo,
                                                   float* __restrict__ warm) {
    const int bid = blockIdx.x;
    const int t = threadIdx.x;
    if (bid >= 4096) {
        int wb = bid - 4096;
        float s = 0.f;
        #pragma unroll
        for (int i = 0; i < 16; ++i) {
            size_t fidx = ((size_t)wb * 4096 + i * 256 + t) * 4;  // float index
            const float* src; size_t off = fidx;
            if (off < 196608)      { src = Wl; }
            else if (off < 393216) { src = Wr; off -= 196608; }
            else if (off < 524288) { src = Wh; off -= 393216; }
            else                   { src = Wo; off -= 524288; }
            float4 v = *(const float4*)&src[off];
            s += v.x + v.y + v.z + v.w;
        }
        warm[wb * 256 + t] = s;   // DCE guard
        return;
    }
    int node = bid * 4 + (t >> 6);
    int lane = t & 63;
    int c = cnt[node];
    if (c > MAXDEG) c = MAXDEG;
    int my = (lane < c) ? col[node * MAXDEG + lane] : 0;
    float a0 = 0.f, a1 = 0.f, a2 = 0.f, a3 = 0.f;
    int j = 0;
    for (; j + 8 <= c; j += 8) {
        float4 v[8];
        #pragma unroll
        for (int q = 0; q < 8; ++q) {
            int s = __shfl(my, j + q);
            v[q] = *(const float4*)&x[(size_t)s * D + lane * 4];
        }
        #pragma unroll
        for (int q = 0; q < 8; ++q) {
            a0 += v[q].x; a1 += v[q].y; a2 += v[q].z; a3 += v[q].w;
        }
    }
    for (; j < c; ++j) {
        int s = __shfl(my, j);
        float4 v = *(const float4*)&x[(size_t)s * D + lane * 4];
        a0 += v.x; a1 += v.y; a2 += v.z; a3 += v.w;
    }
    float id = 1.0f / (float)(c < 1 ? 1 : c);
    float4 r = make_float4(a0 * id, a1 * id, a2 * id, a3 * id);
    *(float4*)&A[(size_t)node * D + lane * 4] = r;
}

// ---------------------------------------------------------------------------
// Telescoped tail (R14 structure, proven 45us; GEMV loads now 32-deep scalar
// batches — 32 VGPR buffers, within the compiler's honored budget):
//   g0=x[r], g1=A[r], g2=mean_{n in(r)} A[n], g3=mean_n mean_{m in(n)} A[m]
//   v0=g1@Wl1+g0@Wr1+b1 ; v1=g2@Wl1+g1@Wr1+b1 ; v2=g3@Wl1+g2@Wr1+b1
//   hB=v1@Wl2+v0@Wr2+b2 ; hA=v2@Wl2+v1@Wr2+b2
//   h =hA@Wl3+hB@Wr3+b3 ; out = MLP head(h)
// ---------------------------------------------------------------------------
__global__ __launch_bounds__(1024) void tail_kernel(
    const int* __restrict__ cnt, const int* __restrict__ col,
    const float* __restrict__ x, const float* __restrict__ A,
    const float* __restrict__ Wl, const float* __restrict__ bl,
    const float* __restrict__ Wr,
    const float* __restrict__ Wh, const float* __restrict__ bh,
    const float* __restrict__ Wo, const float* __restrict__ bo,
    float* __restrict__ out)
{
    __shared__ float g0[D], g1[D], g2[D], g3[D];
    __shared__ float v0[D], v1[D], v2[D], hA[D], hB[D];
    __shared__ float part1[16][D];
    __shared__ float part2[16][D];
    __shared__ int nbr[MAXDEG];
    __shared__ int snr;

    const int b = blockIdx.x, t = threadIdx.x;
    const int w = t >> 6, lane = t & 63;
    const int root = b * NODES_PER_GRAPH;

    if (t == 0) { int cc = cnt[root]; snr = (cc > MAXDEG) ? MAXDEG : cc; }
    __syncthreads();
    const int c0 = snr;
    if (t < c0) nbr[t] = col[root * MAXDEG + t];
    if (t < D) {
        g0[t] = x[(size_t)root * D + t];
        g1[t] = A[(size_t)root * D + t];
    }
    __syncthreads();

    // ---- 1/2-hop gathers of A (R14-proven) ----
    {
        float p1[4] = {0.f, 0.f, 0.f, 0.f}, p2[4] = {0.f, 0.f, 0.f, 0.f};
        for (int i = w; i < c0; i += 16) {
            int n = nbr[i];
            {
                float4 v = *(const float4*)&A[(size_t)n * D + lane * 4];
                p1[0] += v.x; p1[1] += v.y; p1[2] += v.z; p1[3] += v.w;
            }
            int c = cnt[n]; if (c > MAXDEG) c = MAXDEG;
            int my = (lane < c) ? col[n * MAXDEG + lane] : 0;
            float a[4] = {0.f, 0.f, 0.f, 0.f};
            int j = 0;
            for (; j + 8 <= c; j += 8) {
                float4 v[8];
                #pragma unroll
                for (int q = 0; q < 8; ++q) {
                    int s = __shfl(my, j + q);
                    v[q] = *(const float4*)&A[(size_t)s * D + lane * 4];
                }
                #pragma unroll
                for (int q = 0; q < 8; ++q) {
                    a[0] += v[q].x; a[1] += v[q].y; a[2] += v[q].z; a[3] += v[q].w;
                }
            }
            for (; j < c; ++j) {
                int s = __shfl(my, j);
                float4 v = *(const float4*)&A[(size_t)s * D + lane * 4];
                a[0] += v.x; a[1] += v.y; a[2] += v.z; a[3] += v.w;
            }
            float id = 1.0f / (float)(c < 1 ? 1 : c);
            #pragma unroll
            for (int q = 0; q < 4; ++q) p2[q] += a[q] * id;
        }
        #pragma unroll
        for (int q = 0; q < 4; ++q) {
            part1[w][lane * 4 + q] = p1[q];
            part2[w][lane * 4 + q] = p2[q];
        }
        __syncthreads();
        if (t < D) {
            float s1 = 0.f, s2 = 0.f;
            #pragma unroll
            for (int ww = 0; ww < 16; ++ww) { s1 += part1[ww][t]; s2 += part2[ww][t]; }
            float id0 = 1.0f / (float)(c0 < 1 ? 1 : c0);
            g2[t] = s1 * id0;
            g3[t] = s2 * id0;
        }
        __syncthreads();
    }

    const int c = t & 255, kq = t >> 8;
    // ---- layer 1: v0,v1,v2 in one pass; dual-W 32-deep scalar batches ----
    {
        const float* WL = Wl;
        const float* WR = Wr;
        float a0 = 0.f, a1 = 0.f, a2 = 0.f;
        for (int kb = 0; kb < 64; kb += 16) {
            float wl[16], wr[16];
            #pragma unroll
            for (int q = 0; q < 16; ++q) {
                int k = kq * 64 + kb + q;
                wl[q] = WL[(size_t)k * D + c];
                wr[q] = WR[(size_t)k * D + c];
            }
            #pragma unroll
            for (int q = 0; q < 16; ++q) {
                int k = kq * 64 + kb + q;
                float h0 = g0[k], h1 = g1[k], h2 = g2[k], h3 = g3[k];
                a0 += h1 * wl[q] + h0 * wr[q];
                a1 += h2 * wl[q] + h1 * wr[q];
                a2 += h3 * wl[q] + h2 * wr[q];
            }
        }
        part1[kq][c] = a0; part1[4 + kq][c] = a1; part1[8 + kq][c] = a2;
        __syncthreads();
        if (t < D) {
            float s0 = 0.f, s1 = 0.f, s2 = 0.f;
            #pragma unroll
            for (int i = 0; i < 4; ++i) {
                s0 += part1[i][t]; s1 += part1[4 + i][t]; s2 += part1[8 + i][t];
            }
            float bb = bl[t];
            v0[t] = s0 + bb; v1[t] = s1 + bb; v2[t] = s2 + bb;
        }
        __syncthreads();
    }
    // ---- layer 2: hA = v2@Wl2+v1@Wr2+b2 ; hB = v1@Wl2+v0@Wr2+b2 ----
    {
        const float* WL = Wl + (size_t)1 * D * D;
        const float* WR = Wr + (size_t)1 * D * D;
        float aA = 0.f, aB = 0.f;
        for (int kb = 0; kb < 64; kb += 16) {
            float wl[16], wr[16];
            #pragma unroll
            for (int q = 0; q < 16; ++q) {
                int k = kq * 64 + kb + q;
                wl[q] = WL[(size_t)k * D + c];
                wr[q] = WR[(size_t)k * D + c];
            }
            #pragma unroll
            for (int q = 0; q < 16; ++q) {
                int k = kq * 64 + kb + q;
                float h2 = v2[k], h1 = v1[k], h0 = v0[k];
                aA += h2 * wl[q] + h1 * wr[q];
                aB += h1 * wl[q] + h0 * wr[q];
            }
        }
        part1[kq][c] = aA; part1[4 + kq][c] = aB;
        __syncthreads();
        if (t < D) {
            float sA = 0.f, sB = 0.f;
            #pragma unroll
            for (int i = 0; i < 4; ++i) { sA += part1[i][t]; sB += part1[4 + i][t]; }
            float bb = bl[D + t];
            hA[t] = sA + bb; hB[t] = sB + bb;
        }
        __syncthreads();
    }
    // ---- layer 3: v0 <- hA@Wl3 + hB@Wr3 + b3 (head input) ----
    {
        const float* WL = Wl + (size_t)2 * D * D;
        const float* WR = Wr + (size_t)2 * D * D;
        float a = 0.f;
        for (int kb = 0; kb < 64; kb += 16) {
            float wl[16], wr[16];
            #pragma unroll
            for (int q = 0; q < 16; ++q) {
                int k = kq * 64 + kb + q;
                wl[q] = WL[(size_t)k * D + c];
                wr[q] = WR[(size_t)k * D + c];
            }
            #pragma unroll
            for (int q = 0; q < 16; ++q) {
                int k = kq * 64 + kb + q;
                a += hA[k] * wl[q] + hB[k] * wr[q];
            }
        }
        part1[kq][c] = a;
        __syncthreads();
        if (t < D) {
            float s = 0.f;
            #pragma unroll
            for (int i = 0; i < 4; ++i) s += part1[i][t];
            v0[t] = s + bl[2 * D + t];
        }
        __syncthreads();
    }
    // ---- MLP head: single-W, 32-deep scalar batches ----
    for (int l = 0; l < 3; ++l) {
        const float* W = (l < 2) ? Wh + (size_t)l * D * D : Wo;
        float a = 0.f;
        for (int kb = 0; kb < 64; kb += 32) {
            float wv[32];
            #pragma unroll
            for (int q = 0; q < 32; ++q)
                wv[q] = W[(size_t)(kq * 64 + kb + q) * D + c];
            #pragma unroll
            for (int q = 0; q < 32; ++q)
                a += v0[kq * 64 + kb + q] * wv[q];
        }
        part1[kq][c] = a;
        __syncthreads();
        if (t < D) {
            float s = 0.f;
            #pragma unroll
            for (int i = 0; i < 4; ++i) s += part1[i][t];
            float v = s + ((l < 2) ? bh[(size_t)l * D + t] : bo[t]);
            if (l < 2) v0[t] = fmaxf(v, 0.f);
            else       out[(size_t)b * D + t] = v;
        }
        __syncthreads();
    }
}

// ---------------------------------------------------------------------------
extern "C" void kernel_launch(void* const* d_in, const int* in_sizes, int n_in,
                              void* d_out, int out_size, void* d_ws, size_t ws_size,
                              hipStream_t stream) {
    const float* x    = (const float*)d_in[0];
    const int*   edge = (const int*)d_in[1];
    const float* Wl   = (const float*)d_in[2];
    const float* bl   = (const float*)d_in[3];
    const float* Wr   = (const float*)d_in[4];
    const float* Wh   = (const float*)d_in[5];
    const float* bh   = (const float*)d_in[6];
    const float* Wo   = (const float*)d_in[7];
    const float* bo   = (const float*)d_in[8];
    float* out = (float*)d_out;

    char* w = (char*)d_ws;
    auto alloc = [&](size_t bytes) {
        char* p = w;
        w += (bytes + 255) & ~(size_t)255;
        return p;
    };
    int*   cnt  = (int*)  alloc((size_t)N_NODES * 4);
    int*   col  = (int*)  alloc((size_t)N_NODES * MAXDEG * 4);
    float* A    = (float*)alloc((size_t)N_NODES * D * 4);
    float* warm = (float*)alloc((size_t)NWARM * 256 * 4);

    zero_cnt_kernel<<<N_NODES / 256, 256, 0, stream>>>(cnt);
    fill_bucket_kernel<<<N_EDGES / 256, 256, 0, stream>>>(edge, cnt, col);
    aggx_kernel<<<4096 + NWARM, 256, 0, stream>>>(x, cnt, col, A,
                                                  Wl, Wr, Wh, Wo, warm);
    tail_kernel<<<B_GRAPHS, 1024, 0, stream>>>(cnt, col, x, A,
                                               Wl, bl, Wr, Wh, bh, Wo, bo, out);
}

// Round 19
// 129.554 us; speedup vs baseline: 1.0298x; 1.0298x over previous
//
#include <hip/hip_runtime.h>

#define N_NODES 16384
#define N_EDGES 262144
#define D 256
#define B_GRAPHS 32
#define NODES_PER_GRAPH 512   // N_NODES / B_GRAPHS
#define MAXDEG 64             // Poisson(16): P(deg>64) ~ 1e-17

// ---------------------------------------------------------------------------
// zero cnt
// ---------------------------------------------------------------------------
__global__ __launch_bounds__(256) void zero_cnt_kernel(int* __restrict__ cnt) {
    cnt[blockIdx.x * 256 + threadIdx.x] = 0;
}

// ---------------------------------------------------------------------------
// 32x32-tile GEMM helper: acc[4] += (A @ B) tile at (r0,c0), thread-owned
// rows r0+rb+{0,8,16,24}, col c0+(t&31). A staged to LDS (padded 257).
// ---------------------------------------------------------------------------
__device__ __forceinline__ void mm_tile32(const float* __restrict__ A,
                                          const float* __restrict__ B,
                                          int r0, int c0,
                                          float (*As)[257], float acc[4]) {
    const int t = threadIdx.x;
    __syncthreads();   // protect As from previous term's readers
    #pragma unroll
    for (int i = 0; i < 8; ++i) {
        int idx = i * 256 + t;          // float4 slot in 32x256 panel
        int r = idx >> 6, cq = idx & 63;
        float4 v = *(const float4*)&A[(size_t)(r0 + r) * D + cq * 4];
        As[r][cq * 4 + 0] = v.x; As[r][cq * 4 + 1] = v.y;
        As[r][cq * 4 + 2] = v.z; As[r][cq * 4 + 3] = v.w;
    }
    __syncthreads();
    const int c = c0 + (t & 31);
    const int rb = t >> 5;              // 0..7
    #pragma unroll 8
    for (int k = 0; k < 256; ++k) {
        float bv = B[(size_t)k * D + c];
        acc[0] += As[rb][k] * bv;
        acc[1] += As[rb + 8][k] * bv;
        acc[2] += As[rb + 16][k] * bv;
        acc[3] += As[rb + 24][k] * bv;
    }
}

__device__ __forceinline__ void mm_store(float* __restrict__ O, int r0, int c0,
                                         const float acc[4]) {
    const int t = threadIdx.x;
    const int c = c0 + (t & 31);
    const int rb = t >> 5;
    #pragma unroll
    for (int q = 0; q < 4; ++q)
        O[(size_t)(r0 + rb + q * 8) * D + c] = acc[q];
}

// ---------------------------------------------------------------------------
// fill + P stage:
//  bid<1024: bucket fill
//  bid in [1024,1216): P tiles (P2=Wl2@Wl3 ; P1=Wr2@Wl3+Wl2@Wr3 ; P0=Wr2@Wr3)
//  bid==1216: bias2 = b2@(Wl3+Wr3) + b3
// ---------------------------------------------------------------------------
__global__ __launch_bounds__(256) void fill_p_kernel(
    const int* __restrict__ edge, int* __restrict__ cnt, int* __restrict__ col,
    const float* __restrict__ Wl, const float* __restrict__ Wr,
    const float* __restrict__ bl,
    float* __restrict__ P2, float* __restrict__ P1, float* __restrict__ P0,
    float* __restrict__ bias2)
{
    __shared__ float As[32][257];
    const int bid = blockIdx.x;
    const int t = threadIdx.x;
    if (bid < 1024) {
        int e = bid * 256 + t;
        int dst = edge[N_EDGES + e];
        int src = edge[e];
        int slot = atomicAdd(&cnt[dst], 1);
        if (slot < MAXDEG) col[dst * MAXDEG + slot] = src;
        return;
    }
    if (bid == 1216) {
        const float* b2 = bl + D;
        const float* b3 = bl + 2 * D;
        const float* L3 = Wl + (size_t)2 * D * D;
        const float* R3 = Wr + (size_t)2 * D * D;
        float s = 0.f;
        #pragma unroll 8
        for (int k = 0; k < D; ++k)
            s += b2[k] * (L3[(size_t)k * D + t] + R3[(size_t)k * D + t]);
        bias2[t] = s + b3[t];
        return;
    }
    int pb = bid - 1024;                 // 0..191
    int mat = pb >> 6, tile = pb & 63;
    int r0 = (tile >> 3) * 32, c0 = (tile & 7) * 32;
    const float* L2 = Wl + (size_t)1 * D * D;
    const float* R2 = Wr + (size_t)1 * D * D;
    const float* L3 = Wl + (size_t)2 * D * D;
    const float* R3 = Wr + (size_t)2 * D * D;
    float acc[4] = {0.f, 0.f, 0.f, 0.f};
    if (mat == 0) {          // P2 = Wl2 @ Wl3
        mm_tile32(L2, L3, r0, c0, As, acc);
        mm_store(P2, r0, c0, acc);
    } else if (mat == 1) {   // P1 = Wr2 @ Wl3 + Wl2 @ Wr3
        mm_tile32(R2, L3, r0, c0, As, acc);
        mm_tile32(L2, R3, r0, c0, As, acc);
        mm_store(P1, r0, c0, acc);
    } else {                 // P0 = Wr2 @ Wr3
        mm_tile32(R2, R3, r0, c0, As, acc);
        mm_store(P0, r0, c0, acc);
    }
}

// ---------------------------------------------------------------------------
// aggx + Q stage:
//  bid<4096: A[i] = mean_{j in in(i)} x[j]   (one wave per node, R14-proven)
//  bid in [4096,4352): Q tiles
//    Q3=Wl1@P2 ; Q2=Wr1@P2+Wl1@P1 ; Q1=Wr1@P1+Wl1@P0 ; Q0=Wr1@P0
//  bid==4352: beff = b1@(P2+P1+P0) + bias2
// ---------------------------------------------------------------------------
__global__ __launch_bounds__(256) void aggx_q_kernel(
    const float* __restrict__ x, const int* __restrict__ cnt,
    const int* __restrict__ col, float* __restrict__ A,
    const float* __restrict__ Wl, const float* __restrict__ Wr,
    const float* __restrict__ bl,
    const float* __restrict__ P2, const float* __restrict__ P1,
    const float* __restrict__ P0, const float* __restrict__ bias2,
    float* __restrict__ Q, float* __restrict__ beff)
{
    __shared__ float As[32][257];
    const int bid = blockIdx.x;
    const int t = threadIdx.x;
    if (bid < 4096) {
        int node = bid * 4 + (t >> 6);
        int lane = t & 63;
        int c = cnt[node];
        if (c > MAXDEG) c = MAXDEG;
        int my = (lane < c) ? col[node * MAXDEG + lane] : 0;
        float a0 = 0.f, a1 = 0.f, a2 = 0.f, a3 = 0.f;
        int j = 0;
        for (; j + 8 <= c; j += 8) {
            float4 v[8];
            #pragma unroll
            for (int q = 0; q < 8; ++q) {
                int s = __shfl(my, j + q);
                v[q] = *(const float4*)&x[(size_t)s * D + lane * 4];
            }
            #pragma unroll
            for (int q = 0; q < 8; ++q) {
                a0 += v[q].x; a1 += v[q].y; a2 += v[q].z; a3 += v[q].w;
            }
        }
        for (; j < c; ++j) {
            int s = __shfl(my, j);
            float4 v = *(const float4*)&x[(size_t)s * D + lane * 4];
            a0 += v.x; a1 += v.y; a2 += v.z; a3 += v.w;
        }
        float id = 1.0f / (float)(c < 1 ? 1 : c);
        float4 r = make_float4(a0 * id, a1 * id, a2 * id, a3 * id);
        *(float4*)&A[(size_t)node * D + lane * 4] = r;
        return;
    }
    if (bid == 4352) {
        const float* b1 = bl;
        float s = 0.f;
        #pragma unroll 8
        for (int k = 0; k < D; ++k)
            s += b1[k] * (P2[(size_t)k * D + t] + P1[(size_t)k * D + t]
                        + P0[(size_t)k * D + t]);
        beff[t] = s + bias2[t];
        return;
    }
    int qb = bid - 4096;                 // 0..255
    int mat = qb >> 6, tile = qb & 63;
    int r0 = (tile >> 3) * 32, c0 = (tile & 7) * 32;
    const float* L1 = Wl;
    const float* R1 = Wr;
    float acc[4] = {0.f, 0.f, 0.f, 0.f};
    if (mat == 0) {          // Q3 = Wl1 @ P2
        mm_tile32(L1, P2, r0, c0, As, acc);
        mm_store(Q + 3 * (size_t)D * D, r0, c0, acc);
    } else if (mat == 1) {   // Q2 = Wr1 @ P2 + Wl1 @ P1
        mm_tile32(R1, P2, r0, c0, As, acc);
        mm_tile32(L1, P1, r0, c0, As, acc);
        mm_store(Q + 2 * (size_t)D * D, r0, c0, acc);
    } else if (mat == 2) {   // Q1 = Wr1 @ P1 + Wl1 @ P0
        mm_tile32(R1, P1, r0, c0, As, acc);
        mm_tile32(L1, P0, r0, c0, As, acc);
        mm_store(Q + 1 * (size_t)D * D, r0, c0, acc);
    } else {                 // Q0 = Wr1 @ P0
        mm_tile32(R1, P0, r0, c0, As, acc);
        mm_store(Q + 0 * (size_t)D * D, r0, c0, acc);
    }
}

// ---------------------------------------------------------------------------
// Telescoped tail (R14 gather + head verbatim; layers 1-3 folded to ONE
// 4-matrix GEMV phase via precomputed Q):
//   g0=x[r], g1=A[r], g2=mean_{n in(r)} A[n], g3=mean_n mean_{m in(n)} A[m]
//   X3[r] = g3@Q3 + g2@Q2 + g1@Q1 + g0@Q0 + beff ; out = MLP head(X3)
// ---------------------------------------------------------------------------
__global__ __launch_bounds__(1024) void tail_kernel(
    const int* __restrict__ cnt, const int* __restrict__ col,
    const float* __restrict__ x, const float* __restrict__ A,
    const float* __restrict__ Q, const float* __restrict__ beff,
    const float* __restrict__ Wh, const float* __restrict__ bh,
    const float* __restrict__ Wo, const float* __restrict__ bo,
    float* __restrict__ out)
{
    __shared__ float g0[D], g1[D], g2[D], g3[D];
    __shared__ float v0[D];
    __shared__ float part1[16][D];
    __shared__ float part2[16][D];
    __shared__ int nbr[MAXDEG];
    __shared__ int snr;

    const int b = blockIdx.x, t = threadIdx.x;
    const int w = t >> 6, lane = t & 63;
    const int root = b * NODES_PER_GRAPH;

    if (t == 0) { int cc = cnt[root]; snr = (cc > MAXDEG) ? MAXDEG : cc; }
    __syncthreads();
    const int c0 = snr;
    if (t < c0) nbr[t] = col[root * MAXDEG + t];
    if (t < D) {
        g0[t] = x[(size_t)root * D + t];
        g1[t] = A[(size_t)root * D + t];
    }
    __syncthreads();

    // ---- 1/2-hop gathers of A (R14-proven) ----
    {
        float p1[4] = {0.f, 0.f, 0.f, 0.f}, p2[4] = {0.f, 0.f, 0.f, 0.f};
        for (int i = w; i < c0; i += 16) {
            int n = nbr[i];
            {
                float4 v = *(const float4*)&A[(size_t)n * D + lane * 4];
                p1[0] += v.x; p1[1] += v.y; p1[2] += v.z; p1[3] += v.w;
            }
            int c = cnt[n]; if (c > MAXDEG) c = MAXDEG;
            int my = (lane < c) ? col[n * MAXDEG + lane] : 0;
            float a[4] = {0.f, 0.f, 0.f, 0.f};
            int j = 0;
            for (; j + 8 <= c; j += 8) {
                float4 v[8];
                #pragma unroll
                for (int q = 0; q < 8; ++q) {
                    int s = __shfl(my, j + q);
                    v[q] = *(const float4*)&A[(size_t)s * D + lane * 4];
                }
                #pragma unroll
                for (int q = 0; q < 8; ++q) {
                    a[0] += v[q].x; a[1] += v[q].y; a[2] += v[q].z; a[3] += v[q].w;
                }
            }
            for (; j < c; ++j) {
                int s = __shfl(my, j);
                float4 v = *(const float4*)&A[(size_t)s * D + lane * 4];
                a[0] += v.x; a[1] += v.y; a[2] += v.z; a[3] += v.w;
            }
            float id = 1.0f / (float)(c < 1 ? 1 : c);
            #pragma unroll
            for (int q = 0; q < 4; ++q) p2[q] += a[q] * id;
        }
        #pragma unroll
        for (int q = 0; q < 4; ++q) {
            part1[w][lane * 4 + q] = p1[q];
            part2[w][lane * 4 + q] = p2[q];
        }
        __syncthreads();
        if (t < D) {
            float s1 = 0.f, s2 = 0.f;
            #pragma unroll
            for (int ww = 0; ww < 16; ++ww) { s1 += part1[ww][t]; s2 += part2[ww][t]; }
            float id0 = 1.0f / (float)(c0 < 1 ? 1 : c0);
            g2[t] = s1 * id0;
            g3[t] = s2 * id0;
        }
        __syncthreads();
    }

    const int c = t & 255, kq = t >> 8;
    // ---- single folded phase: X3 = g3@Q3 + g2@Q2 + g1@Q1 + g0@Q0 + beff ----
    {
        const float* Q0 = Q;
        const float* Q1 = Q + (size_t)D * D;
        const float* Q2 = Q + 2 * (size_t)D * D;
        const float* Q3 = Q + 3 * (size_t)D * D;
        float a = 0.f;
        #pragma unroll 8
        for (int k0 = 0; k0 < 64; ++k0) {
            int k = kq * 64 + k0;
            a += g0[k] * Q0[(size_t)k * D + c] + g1[k] * Q1[(size_t)k * D + c]
               + g2[k] * Q2[(size_t)k * D + c] + g3[k] * Q3[(size_t)k * D + c];
        }
        part1[kq][c] = a;
        __syncthreads();
        if (t < D) {
            float s = part1[0][t] + part1[1][t] + part1[2][t] + part1[3][t];
            v0[t] = s + beff[t];
        }
        __syncthreads();
    }
    // ---- MLP head (R14-proven) ----
    for (int l = 0; l < 3; ++l) {
        const float* W = (l < 2) ? Wh + (size_t)l * D * D : Wo;
        float a = 0.f;
        #pragma unroll
        for (int k0 = 0; k0 < 64; k0 += 8) {
            float wv[8];
            #pragma unroll
            for (int j = 0; j < 8; ++j)
                wv[j] = W[(size_t)(kq * 64 + k0 + j) * D + c];
            #pragma unroll
            for (int j = 0; j < 8; ++j)
                a += v0[kq * 64 + k0 + j] * wv[j];
        }
        part1[kq][c] = a;
        __syncthreads();
        if (t < D) {
            float v = part1[0][t] + part1[1][t] + part1[2][t] + part1[3][t]
                    + ((l < 2) ? bh[(size_t)l * D + t] : bo[t]);
            if (l < 2) v0[t] = fmaxf(v, 0.f);
            else       out[(size_t)b * D + t] = v;
        }
        __syncthreads();
    }
}

// ---------------------------------------------------------------------------
extern "C" void kernel_launch(void* const* d_in, const int* in_sizes, int n_in,
                              void* d_out, int out_size, void* d_ws, size_t ws_size,
                              hipStream_t stream) {
    const float* x    = (const float*)d_in[0];
    const int*   edge = (const int*)d_in[1];
    const float* Wl   = (const float*)d_in[2];
    const float* bl   = (const float*)d_in[3];
    const float* Wr   = (const float*)d_in[4];
    const float* Wh   = (const float*)d_in[5];
    const float* bh   = (const float*)d_in[6];
    const float* Wo   = (const float*)d_in[7];
    const float* bo   = (const float*)d_in[8];
    float* out = (float*)d_out;

    char* w = (char*)d_ws;
    auto alloc = [&](size_t bytes) {
        char* p = w;
        w += (bytes + 255) & ~(size_t)255;
        return p;
    };
    int*   cnt   = (int*)  alloc((size_t)N_NODES * 4);
    int*   col   = (int*)  alloc((size_t)N_NODES * MAXDEG * 4);
    float* A     = (float*)alloc((size_t)N_NODES * D * 4);
    float* P2    = (float*)alloc((size_t)D * D * 4);
    float* P1    = (float*)alloc((size_t)D * D * 4);
    float* P0    = (float*)alloc((size_t)D * D * 4);
    float* bias2 = (float*)alloc((size_t)D * 4);
    float* Q     = (float*)alloc((size_t)4 * D * D * 4);
    float* beff  = (float*)alloc((size_t)D * 4);

    zero_cnt_kernel<<<N_NODES / 256, 256, 0, stream>>>(cnt);
    fill_p_kernel<<<1217, 256, 0, stream>>>(edge, cnt, col, Wl, Wr, bl,
                                            P2, P1, P0, bias2);
    aggx_q_kernel<<<4353, 256, 0, stream>>>(x, cnt, col, A, Wl, Wr, bl,
                                            P2, P1, P0, bias2, Q, beff);
    tail_kernel<<<B_GRAPHS, 1024, 0, stream>>>(cnt, col, x, A, Q, beff,
                                               Wh, bh, Wo, bo, out);
}